// Round 1
// baseline (1498.519 us; speedup 1.0000x reference)
//
#include <hip/hip_runtime.h>
#include <math.h>

#define DIMC 192
#define C3 576
#define NHEADS 8
#define CDh 24
#define HWN 16384
#define WIDTH 128
#define NBATCH 8

// ============ K1: conv1x1 per batch: qkv_raw[576][16384] = W(576x192) @ x_b + b ============
// grid (128 n-tiles, 9 m-tiles), block 256. fp32 register-tiled GEMM: 64(M)x128(N), thread 4x8.
__global__ __launch_bounds__(256) void k1_conv1x1(const float* __restrict__ x,
                                                  const float* __restrict__ W,
                                                  const float* __restrict__ bias,
                                                  float* __restrict__ out, int b) {
    __shared__ float A_s[32][68];   // [k][o], padded stride 68 (16B-aligned rows)
    __shared__ float B_s[32][128];  // [k][n]
    const float* xb = x + (size_t)b * DIMC * HWN;
    const int n0 = blockIdx.x * 128;
    const int o0 = blockIdx.y * 64;
    const int tid = threadIdx.x;
    const int pt = tid & 15, ot = tid >> 4;
    float acc[4][8];
#pragma unroll
    for (int i = 0; i < 4; i++)
#pragma unroll
        for (int j = 0; j < 8; j++) acc[i][j] = 0.f;

    for (int kc = 0; kc < DIMC; kc += 32) {
        __syncthreads();
        // stage A = W[o0..+64][kc..+32] transposed -> A_s[k][o]
#pragma unroll
        for (int f = tid; f < 512; f += 256) {
            int row = f >> 3, j = f & 7;
            float4 v = *(const float4*)&W[(o0 + row) * DIMC + kc + j * 4];
            A_s[j * 4 + 0][row] = v.x; A_s[j * 4 + 1][row] = v.y;
            A_s[j * 4 + 2][row] = v.z; A_s[j * 4 + 3][row] = v.w;
        }
        // stage B = x[kc..+32][n0..+128]
#pragma unroll
        for (int f = tid; f < 1024; f += 256) {
            int r = f >> 5, c4 = f & 31;
            *(float4*)&B_s[r][c4 * 4] = *(const float4*)&xb[(size_t)(kc + r) * HWN + n0 + c4 * 4];
        }
        __syncthreads();
#pragma unroll
        for (int kk = 0; kk < 32; kk++) {
            float a[4], bv[8];
            *(float4*)a = *(const float4*)&A_s[kk][ot * 4];
            *(float4*)(bv) = *(const float4*)&B_s[kk][pt * 8];
            *(float4*)(bv + 4) = *(const float4*)&B_s[kk][pt * 8 + 4];
#pragma unroll
            for (int i = 0; i < 4; i++)
#pragma unroll
                for (int j = 0; j < 8; j++) acc[i][j] = fmaf(a[i], bv[j], acc[i][j]);
        }
    }
#pragma unroll
    for (int i = 0; i < 4; i++) {
        int o = o0 + ot * 4 + i;
        float bs = bias[o];
        float4 v0 = {acc[i][0] + bs, acc[i][1] + bs, acc[i][2] + bs, acc[i][3] + bs};
        float4 v1 = {acc[i][4] + bs, acc[i][5] + bs, acc[i][6] + bs, acc[i][7] + bs};
        *(float4*)&out[(size_t)o * HWN + n0 + pt * 8] = v0;
        *(float4*)&out[(size_t)o * HWN + n0 + pt * 8 + 4] = v1;
    }
}

// ============ K2: depthwise 3x3 (pad 1) + on-the-fly Gram/sumsq partials; writes only v ============
// grid (64 stripes of 2 rows, 8 heads), block 256 (one pixel/thread), arg b.
// For head h: 72 channels (q,k,v of that head). q,k go to LDS; v to d_out (used as v scratch).
// Per-block partials: 576 gram pairs + 24 q-sumsq + 24 k-sumsq = 624 values (deterministic, no atomics).
__global__ __launch_bounds__(256) void k2_dw(const float* __restrict__ qkv,
                                             const float* __restrict__ wdw,
                                             const float* __restrict__ bdw,
                                             float* __restrict__ vout,
                                             float* __restrict__ part, int b) {
    __shared__ float in_s[4][128];
    __shared__ float qk_s[48][257];
    const int stripe = blockIdx.x, h = blockIdx.y;
    const int tid = threadIdx.x;
    const int r0 = stripe * 2;
    const int row_local = tid >> 7;  // 0..1
    const int col = tid & 127;
    const int orow = r0 + row_local;

    for (int ci = 0; ci < 72; ci++) {
        int g = ci / 24, cc = ci % 24;
        int ch = g * DIMC + h * CDh + cc;
        const float* src = qkv + (size_t)ch * HWN;
        __syncthreads();
#pragma unroll
        for (int f = tid; f < 512; f += 256) {
            int rl = f >> 7, c = f & 127;
            int gr = r0 - 1 + rl;
            in_s[rl][c] = (gr >= 0 && gr < 128) ? src[gr * WIDTH + c] : 0.f;
        }
        __syncthreads();
        float wreg[9];
#pragma unroll
        for (int t = 0; t < 9; t++) wreg[t] = wdw[ch * 9 + t];
        float acc = bdw[ch];
#pragma unroll
        for (int dr = -1; dr <= 1; dr++)
#pragma unroll
            for (int dc = -1; dc <= 1; dc++) {
                int c2 = col + dc;
                float v = (c2 >= 0 && c2 < 128) ? in_s[row_local + 1 + dr][c2] : 0.f;
                acc = fmaf(v, wreg[(dr + 1) * 3 + (dc + 1)], acc);
            }
        if (g == 2) {
            vout[((size_t)b * DIMC + h * CDh + cc) * HWN + orow * WIDTH + col] = acc;
        } else {
            qk_s[g * CDh + cc][tid] = acc;
        }
    }
    __syncthreads();
    const int bh = b * NHEADS + h;
    float* pdst = part + ((size_t)bh * 64 + stripe) * 624;
    for (int ti = tid; ti < 624; ti += 256) {
        float s = 0.f;
        if (ti < 576) {
            int c = ti / 24, d = ti % 24;
            const float* qr = qk_s[c];
            const float* kr = qk_s[24 + d];
            for (int i = 0; i < 256; i++) {
                int p = (i + tid) & 255;  // skewed start: spread LDS banks
                s = fmaf(qr[p], kr[p], s);
            }
        } else {
            int row = (ti < 600) ? (ti - 576) : (24 + (ti - 600));
            const float* qr = qk_s[row];
            for (int i = 0; i < 256; i++) {
                int p = (i + tid) & 255;
                s = fmaf(qr[p], qr[p], s);
            }
        }
        pdst[ti] = s;
    }
}

// ============ K3: reduce stripe partials (fixed order -> deterministic) ============
// grid 64 (b*8+h), block 256.
__global__ void k3_reduce(const float* __restrict__ part, float* __restrict__ G,
                          float* __restrict__ nq, float* __restrict__ nk) {
    int bh = blockIdx.x;
    int b = bh >> 3, h = bh & 7;
    for (int ti = threadIdx.x; ti < 624; ti += 256) {
        const float* p = part + (size_t)bh * 64 * 624 + ti;
        float s = 0.f;
        for (int st = 0; st < 64; st++) s += p[st * 624];
        if (ti < 576) G[bh * 576 + ti] = s;
        else if (ti < 600) nq[b * DIMC + h * CDh + (ti - 576)] = s;
        else nk[b * DIMC + h * CDh + (ti - 600)] = s;
    }
}

// ============ K4a: attn = G/(||q|| ||k||) * temp; 4 top-k sparse softmaxes -> A_eff ============
// grid (8 h, 8 b), block 64 (thread = row r of 24).
__global__ void k4a_attn(const float* __restrict__ G, const float* __restrict__ nq,
                         const float* __restrict__ nk, const float* __restrict__ temp,
                         const float* __restrict__ a1, const float* __restrict__ a2,
                         const float* __restrict__ a3, const float* __restrict__ a4,
                         float* __restrict__ Aeff) {
    int h = blockIdx.x, b = blockIdx.y;
    int bh = b * NHEADS + h;
    int r = threadIdx.x;
    if (r >= CDh) return;
    float t = temp[h];
    float aw[4] = {a1[0], a2[0], a3[0], a4[0]};
    const int kks[4] = {12, 16, 18, 19};
    float qn = fmaxf(sqrtf(nq[b * DIMC + h * CDh + r]), 1e-12f);
    float av[24];
    for (int d = 0; d < 24; d++) {
        float kn = fmaxf(sqrtf(nk[b * DIMC + h * CDh + d]), 1e-12f);
        av[d] = G[bh * 576 + r * 24 + d] / (qn * kn) * t;
    }
    // rank with jax top_k tie-break (earlier index wins)
    int rank[24];
    float m = -1e30f;
    for (int d = 0; d < 24; d++) {
        int rk = 0;
        for (int e = 0; e < 24; e++)
            rk += (av[e] > av[d]) || (av[e] == av[d] && e < d);
        rank[d] = rk;
        m = fmaxf(m, av[d]);
    }
    float ex[24], outv[24];
    for (int d = 0; d < 24; d++) { ex[d] = expf(av[d] - m); outv[d] = 0.f; }
    for (int i = 0; i < 4; i++) {
        float Z = 0.f;
        for (int d = 0; d < 24; d++) if (rank[d] < kks[i]) Z += ex[d];
        float inv = aw[i] / Z;
        for (int d = 0; d < 24; d++) if (rank[d] < kks[i]) outv[d] += ex[d] * inv;
    }
    for (int d = 0; d < 24; d++) Aeff[(bh * 24 + r) * 24 + d] = outv[d];
}

// ============ K4b: M_b = W_proj @ blockdiag(A_eff)  (192x192 per batch) ============
// grid 8 (b), block 256.
__global__ void k4b_mmat(const float* __restrict__ Wp, const float* __restrict__ Aeff,
                         float* __restrict__ M) {
    int b = blockIdx.x;
    for (int e = threadIdx.x; e < DIMC * DIMC; e += 256) {
        int o = e / DIMC, j = e % DIMC;
        int h = j / CDh, d = j % CDh;
        const float* wrow = Wp + o * DIMC + h * CDh;
        const float* acol = Aeff + (size_t)((b * NHEADS + h) * CDh) * CDh + d;
        float s = 0.f;
        for (int c = 0; c < CDh; c++) s = fmaf(wrow[c], acol[c * CDh], s);
        M[((size_t)b * DIMC + o) * DIMC + j] = s;
    }
}

// ============ K5: in-place y = M_b @ v + b_proj on d_out (v staged to LDS first) ============
// grid (256 pixel-chunks of 64, 8 b), block 256. Tile 192(M)x64(N), thread 12x4.
__global__ __launch_bounds__(256) void k5_proj(float* __restrict__ vy, const float* __restrict__ M,
                                               const float* __restrict__ bias) {
    __shared__ float v_s[192][68];
    __shared__ float M_s[32][196];
    const int b = blockIdx.y;
    const int n0 = blockIdx.x * 64;
    const int tid = threadIdx.x;
    float* vb = vy + (size_t)b * DIMC * HWN;
    // stage entire v block (all 192 channels x 64 pixels) BEFORE any overwrite
#pragma unroll
    for (int f = tid; f < 3072; f += 256) {
        int row = f >> 4, q = f & 15;
        *(float4*)&v_s[row][q * 4] = *(const float4*)&vb[(size_t)row * HWN + n0 + q * 4];
    }
    const float* Mb = M + (size_t)b * DIMC * DIMC;
    const int pt = tid & 15, ot = tid >> 4;
    float acc[12][4];
#pragma unroll
    for (int i = 0; i < 12; i++)
#pragma unroll
        for (int j = 0; j < 4; j++) acc[i][j] = 0.f;

    for (int kc = 0; kc < DIMC; kc += 32) {
        __syncthreads();
#pragma unroll
        for (int f = tid; f < 1536; f += 256) {
            int row = f >> 3, j4 = f & 7;
            float4 w = *(const float4*)&Mb[row * DIMC + kc + j4 * 4];
            M_s[j4 * 4 + 0][row] = w.x; M_s[j4 * 4 + 1][row] = w.y;
            M_s[j4 * 4 + 2][row] = w.z; M_s[j4 * 4 + 3][row] = w.w;
        }
        __syncthreads();
#pragma unroll
        for (int kk = 0; kk < 32; kk++) {
            float a[12], bv[4];
            *(float4*)(a) = *(const float4*)&M_s[kk][ot * 12];
            *(float4*)(a + 4) = *(const float4*)&M_s[kk][ot * 12 + 4];
            *(float4*)(a + 8) = *(const float4*)&M_s[kk][ot * 12 + 8];
            *(float4*)bv = *(const float4*)&v_s[kc + kk][pt * 4];
#pragma unroll
            for (int i = 0; i < 12; i++)
#pragma unroll
                for (int j = 0; j < 4; j++) acc[i][j] = fmaf(a[i], bv[j], acc[i][j]);
        }
    }
#pragma unroll
    for (int i = 0; i < 12; i++) {
        int o = ot * 12 + i;
        float bs = bias[o];
        float4 w = {acc[i][0] + bs, acc[i][1] + bs, acc[i][2] + bs, acc[i][3] + bs};
        *(float4*)&vb[(size_t)o * HWN + n0 + pt * 4] = w;
    }
}

extern "C" void kernel_launch(void* const* d_in, const int* in_sizes, int n_in,
                              void* d_out, int out_size, void* d_ws, size_t ws_size,
                              hipStream_t stream) {
    const float* x     = (const float*)d_in[0];
    const float* wqkv  = (const float*)d_in[1];
    const float* bqkv  = (const float*)d_in[2];
    const float* wdw   = (const float*)d_in[3];
    const float* bdw   = (const float*)d_in[4];
    const float* wproj = (const float*)d_in[5];
    const float* bproj = (const float*)d_in[6];
    const float* temp  = (const float*)d_in[7];
    const float* a1    = (const float*)d_in[8];
    const float* a2    = (const float*)d_in[9];
    const float* a3    = (const float*)d_in[10];
    const float* a4    = (const float*)d_in[11];
    float* out = (float*)d_out;

    // ws layout (floats). Total ~49 MB.
    float* ws = (float*)d_ws;
    size_t o_qkv  = 0;                               // per-batch qkv_raw: 576*16384
    size_t o_part = o_qkv + (size_t)C3 * HWN;        // 64 bh * 64 stripes * 624
    size_t o_G    = o_part + (size_t)64 * 64 * 624;  // 64*576
    size_t o_nq   = o_G + (size_t)64 * 576;          // 8*192 (sumsq)
    size_t o_nk   = o_nq + (size_t)NBATCH * DIMC;
    size_t o_A    = o_nk + (size_t)NBATCH * DIMC;    // 64*576
    size_t o_M    = o_A + (size_t)64 * 576;          // 8*192*192
    float* qkv_raw = ws + o_qkv;
    float* part    = ws + o_part;
    float* G       = ws + o_G;
    float* nq      = ws + o_nq;
    float* nk      = ws + o_nk;
    float* Aeff    = ws + o_A;
    float* M       = ws + o_M;

    for (int b = 0; b < NBATCH; b++) {
        k1_conv1x1<<<dim3(128, 9), 256, 0, stream>>>(x, wqkv, bqkv, qkv_raw, b);
        k2_dw<<<dim3(64, 8), 256, 0, stream>>>(qkv_raw, wdw, bdw, out, part, b);
    }
    k3_reduce<<<64, 256, 0, stream>>>(part, G, nq, nk);
    k4a_attn<<<dim3(8, 8), 64, 0, stream>>>(G, nq, nk, temp, a1, a2, a3, a4, Aeff);
    k4b_mmat<<<8, 256, 0, stream>>>(wproj, Aeff, M);
    k5_proj<<<dim3(256, 8), 256, 0, stream>>>(out, M, bproj);
}

// Round 2
// 895.636 us; speedup vs baseline: 1.6731x; 1.6731x over previous
//
#include <hip/hip_runtime.h>
#include <math.h>

#define DIMC 192
#define C3 576
#define NHEADS 8
#define CDh 24
#define HWN 16384
#define WIDTH 128
#define NBATCH 8

// ============ K1: conv1x1 per batch: qkv_raw[576][16384] = W(576x192) @ x_b + b ============
// grid (128 n-tiles, 6 m-tiles), block 256. Block tile 96(M)x128(N), thread 6x8 (split 2x f4 in N).
__global__ __launch_bounds__(256) void k1_conv1x1(const float* __restrict__ x,
                                                  const float* __restrict__ W,
                                                  const float* __restrict__ bias,
                                                  float* __restrict__ out, int b) {
    __shared__ float A_s[32 * 100];  // [k][o0..96], stride 100
    __shared__ float B_s[32 * 132];  // [k][n0..128], stride 132
    const float* xb = x + (size_t)b * DIMC * HWN;
    const int n0 = blockIdx.x * 128;
    const int o0 = blockIdx.y * 96;
    const int tid = threadIdx.x;
    const int pt = tid & 15, ot = tid >> 4;  // pt: 16 in N, ot: 16 in M
    float acc[6][8];
#pragma unroll
    for (int i = 0; i < 6; i++)
#pragma unroll
        for (int j = 0; j < 8; j++) acc[i][j] = 0.f;

    for (int kc = 0; kc < DIMC; kc += 32) {
        __syncthreads();
        // stage A = W[o0..+96][kc..+32] transposed -> A_s[k][o]  (768 float4s)
#pragma unroll
        for (int f = tid; f < 768; f += 256) {
            int row = f >> 3, j = f & 7;
            float4 v = *(const float4*)&W[(size_t)(o0 + row) * DIMC + kc + j * 4];
            A_s[(j * 4 + 0) * 100 + row] = v.x; A_s[(j * 4 + 1) * 100 + row] = v.y;
            A_s[(j * 4 + 2) * 100 + row] = v.z; A_s[(j * 4 + 3) * 100 + row] = v.w;
        }
        // stage B = x[kc..+32][n0..+128]  (1024 float4s)
#pragma unroll
        for (int f = tid; f < 1024; f += 256) {
            int r = f >> 5, c4 = f & 31;
            *(float4*)&B_s[r * 132 + c4 * 4] =
                *(const float4*)&xb[(size_t)(kc + r) * HWN + n0 + c4 * 4];
        }
        __syncthreads();
#pragma unroll
        for (int kk = 0; kk < 32; kk++) {
            float a6[6], bv[8];
            *(float2*)(a6 + 0) = *(const float2*)&A_s[kk * 100 + ot * 6 + 0];
            *(float2*)(a6 + 2) = *(const float2*)&A_s[kk * 100 + ot * 6 + 2];
            *(float2*)(a6 + 4) = *(const float2*)&A_s[kk * 100 + ot * 6 + 4];
            *(float4*)(bv + 0) = *(const float4*)&B_s[kk * 132 + pt * 4];
            *(float4*)(bv + 4) = *(const float4*)&B_s[kk * 132 + 64 + pt * 4];
#pragma unroll
            for (int i = 0; i < 6; i++)
#pragma unroll
                for (int j = 0; j < 8; j++) acc[i][j] = fmaf(a6[i], bv[j], acc[i][j]);
        }
    }
#pragma unroll
    for (int i = 0; i < 6; i++) {
        int o = o0 + ot * 6 + i;
        float bs = bias[o];
        float4 v0 = {acc[i][0] + bs, acc[i][1] + bs, acc[i][2] + bs, acc[i][3] + bs};
        float4 v1 = {acc[i][4] + bs, acc[i][5] + bs, acc[i][6] + bs, acc[i][7] + bs};
        *(float4*)&out[(size_t)o * HWN + n0 + pt * 4] = v0;
        *(float4*)&out[(size_t)o * HWN + n0 + 64 + pt * 4] = v1;
    }
}

// ============ K2: depthwise 3x3 + on-the-fly Gram/sumsq partials; writes only v ============
// grid (64 stripes of 2 rows, 8 heads), block 256 (one pixel/thread), arg b.
__global__ __launch_bounds__(256) void k2_dw(const float* __restrict__ qkv,
                                             const float* __restrict__ wdw,
                                             const float* __restrict__ bdw,
                                             float* __restrict__ vout,
                                             float* __restrict__ part, int b) {
    __shared__ float qk_s[256 * 49];  // [pixel][48 qk channels + pad]
    __shared__ float pool[4096];      // chunk staging [8][4][128]; later gacc[4*576]+nacc[4*48]
    const int stripe = blockIdx.x, h = blockIdx.y;
    const int tid = threadIdx.x;
    const int r0 = stripe * 2;
    const int rl_out = tid >> 7;  // 0..1
    const int col = tid & 127;
    const int orow = r0 + rl_out;

    // 9 chunks of 8 channels: chunks 0-2=q, 3-5=k, 6-8=v
    for (int chunk = 0; chunk < 9; chunk++) {
        const int g = chunk / 3;
        const int c_base = (chunk % 3) * 8;
        __syncthreads();
        // stage 8 channels x 4 rows x 128 cols (1024 float4s)
#pragma unroll
        for (int f = tid; f < 1024; f += 256) {
            int cc = f >> 7, rl = (f >> 5) & 3, c4 = f & 31;
            int gr = r0 - 1 + rl;
            int ch = g * DIMC + h * CDh + c_base + cc;
            float4 v;
            if (gr >= 0 && gr < 128)
                v = *(const float4*)&qkv[(size_t)ch * HWN + gr * WIDTH + c4 * 4];
            else
                v = make_float4(0.f, 0.f, 0.f, 0.f);
            *(float4*)&pool[(cc * 4 + rl) * 128 + c4 * 4] = v;
        }
        __syncthreads();
#pragma unroll
        for (int cc = 0; cc < 8; cc++) {
            int ch = g * DIMC + h * CDh + c_base + cc;
            const float* wp = &wdw[ch * 9];
            float acc = bdw[ch];
            const float* in0 = &pool[cc * 512];
#pragma unroll
            for (int dr = 0; dr < 3; dr++) {
                const float* row = in0 + (rl_out + dr) * 128;
                float left  = (col > 0)   ? row[col - 1] : 0.f;
                float mid   = row[col];
                float right = (col < 127) ? row[col + 1] : 0.f;
                acc = fmaf(left, wp[dr * 3 + 0],
                      fmaf(mid, wp[dr * 3 + 1],
                      fmaf(right, wp[dr * 3 + 2], acc)));
            }
            if (g == 2)
                vout[((size_t)b * DIMC + h * CDh + c_base + cc) * HWN + orow * WIDTH + col] = acc;
            else
                qk_s[tid * 49 + g * CDh + c_base + cc] = acc;
        }
    }
    __syncthreads();  // qk_s complete; pool free for reuse

    // Gram: thread = (ct 8, dt 8, pg 4); 3x3 register tile over 64 pixels
    const int ct = (tid & 7) * 3;
    const int dt = ((tid >> 3) & 7) * 3;
    const int pg = tid >> 6;
    float gval[3][3];
#pragma unroll
    for (int i = 0; i < 3; i++)
#pragma unroll
        for (int j = 0; j < 3; j++) gval[i][j] = 0.f;
#pragma unroll 4
    for (int p = pg * 64; p < pg * 64 + 64; p++) {
        const float* base = &qk_s[p * 49];
        float qv[3], kv[3];
        qv[0] = base[ct]; qv[1] = base[ct + 1]; qv[2] = base[ct + 2];
        kv[0] = base[24 + dt]; kv[1] = base[24 + dt + 1]; kv[2] = base[24 + dt + 2];
#pragma unroll
        for (int i = 0; i < 3; i++)
#pragma unroll
            for (int j = 0; j < 3; j++) gval[i][j] = fmaf(qv[i], kv[j], gval[i][j]);
    }
    // norms: threads 0..191: ch = tid%48, pixel group tid/48
    float nval = 0.f;
    int nch = 0, npg = 0;
    if (tid < 192) {
        npg = tid / 48;
        nch = tid - npg * 48;
#pragma unroll 4
        for (int p = npg * 64; p < npg * 64 + 64; p++) {
            float v = qk_s[p * 49 + nch];
            nval = fmaf(v, v, nval);
        }
    }
    __syncthreads();  // conv-phase pool reads done everywhere (already synced above); ensure before writes
    float* gacc = pool;          // [4][576]
    float* nacc = pool + 2304;   // [4][48]
#pragma unroll
    for (int i = 0; i < 3; i++)
#pragma unroll
        for (int j = 0; j < 3; j++) gacc[pg * 576 + (ct + i) * 24 + (dt + j)] = gval[i][j];
    if (tid < 192) nacc[npg * 48 + nch] = nval;
    __syncthreads();
    float* pdst = part + ((size_t)(b * NHEADS + h) * 64 + stripe) * 624;
    for (int ti = tid; ti < 624; ti += 256) {
        float s;
        if (ti < 576)
            s = gacc[ti] + gacc[576 + ti] + gacc[1152 + ti] + gacc[1728 + ti];
        else {
            int ch = ti - 576;
            s = nacc[ch] + nacc[48 + ch] + nacc[96 + ch] + nacc[144 + ch];
        }
        pdst[ti] = s;
    }
}

// ============ K3: reduce stripe partials (fixed order -> deterministic) ============
__global__ void k3_reduce(const float* __restrict__ part, float* __restrict__ G,
                          float* __restrict__ nq, float* __restrict__ nk) {
    int bh = blockIdx.x;
    int b = bh >> 3, h = bh & 7;
    for (int ti = threadIdx.x; ti < 624; ti += 256) {
        const float* p = part + (size_t)bh * 64 * 624 + ti;
        float s = 0.f;
        for (int st = 0; st < 64; st++) s += p[st * 624];
        if (ti < 576) G[bh * 576 + ti] = s;
        else if (ti < 600) nq[b * DIMC + h * CDh + (ti - 576)] = s;
        else nk[b * DIMC + h * CDh + (ti - 600)] = s;
    }
}

// ============ K4a: attn + 4 top-k sparse softmaxes -> A_eff ============
__global__ void k4a_attn(const float* __restrict__ G, const float* __restrict__ nq,
                         const float* __restrict__ nk, const float* __restrict__ temp,
                         const float* __restrict__ a1, const float* __restrict__ a2,
                         const float* __restrict__ a3, const float* __restrict__ a4,
                         float* __restrict__ Aeff) {
    int h = blockIdx.x, b = blockIdx.y;
    int bh = b * NHEADS + h;
    int r = threadIdx.x;
    if (r >= CDh) return;
    float t = temp[h];
    float aw[4] = {a1[0], a2[0], a3[0], a4[0]};
    const int kks[4] = {12, 16, 18, 19};
    float qn = fmaxf(sqrtf(nq[b * DIMC + h * CDh + r]), 1e-12f);
    float av[24];
    for (int d = 0; d < 24; d++) {
        float kn = fmaxf(sqrtf(nk[b * DIMC + h * CDh + d]), 1e-12f);
        av[d] = G[bh * 576 + r * 24 + d] / (qn * kn) * t;
    }
    int rank[24];
    float m = -1e30f;
    for (int d = 0; d < 24; d++) {
        int rk = 0;
        for (int e = 0; e < 24; e++)
            rk += (av[e] > av[d]) || (av[e] == av[d] && e < d);
        rank[d] = rk;
        m = fmaxf(m, av[d]);
    }
    float ex[24], outv[24];
    for (int d = 0; d < 24; d++) { ex[d] = expf(av[d] - m); outv[d] = 0.f; }
    for (int i = 0; i < 4; i++) {
        float Z = 0.f;
        for (int d = 0; d < 24; d++) if (rank[d] < kks[i]) Z += ex[d];
        float inv = aw[i] / Z;
        for (int d = 0; d < 24; d++) if (rank[d] < kks[i]) outv[d] += ex[d] * inv;
    }
    for (int d = 0; d < 24; d++) Aeff[(bh * 24 + r) * 24 + d] = outv[d];
}

// ============ K4b: M_b = W_proj @ blockdiag(A_eff) ============
// grid (8 b, 6 chunks), block 256.
__global__ void k4b_mmat(const float* __restrict__ Wp, const float* __restrict__ Aeff,
                         float* __restrict__ M) {
    int b = blockIdx.x;
    int e0 = blockIdx.y * 6144;
    for (int e = e0 + threadIdx.x; e < e0 + 6144; e += 256) {
        int o = e / DIMC, j = e % DIMC;
        int h = j / CDh, d = j % CDh;
        const float* wrow = Wp + o * DIMC + h * CDh;
        const float* acol = Aeff + (size_t)((b * NHEADS + h) * CDh) * CDh + d;
        float s = 0.f;
        for (int c = 0; c < CDh; c++) s = fmaf(wrow[c], acol[c * CDh], s);
        M[((size_t)b * DIMC + o) * DIMC + j] = s;
    }
}

// ============ K5 fast: y = M_b @ v + b_proj (v in ws), same tiling as K1 ============
// grid (128 n-tiles, 2 m-tiles, 8 b), block 256.
__global__ __launch_bounds__(256) void k5_fast(const float* __restrict__ v,
                                               const float* __restrict__ M,
                                               const float* __restrict__ bias,
                                               float* __restrict__ y) {
    __shared__ float A_s[32 * 100];
    __shared__ float B_s[32 * 132];
    const int b = blockIdx.z;
    const float* vb = v + (size_t)b * DIMC * HWN;
    const float* Mb = M + (size_t)b * DIMC * DIMC;
    float* yb = y + (size_t)b * DIMC * HWN;
    const int n0 = blockIdx.x * 128;
    const int o0 = blockIdx.y * 96;
    const int tid = threadIdx.x;
    const int pt = tid & 15, ot = tid >> 4;
    float acc[6][8];
#pragma unroll
    for (int i = 0; i < 6; i++)
#pragma unroll
        for (int j = 0; j < 8; j++) acc[i][j] = 0.f;

    for (int kc = 0; kc < DIMC; kc += 32) {
        __syncthreads();
#pragma unroll
        for (int f = tid; f < 768; f += 256) {
            int row = f >> 3, j = f & 7;
            float4 w = *(const float4*)&Mb[(size_t)(o0 + row) * DIMC + kc + j * 4];
            A_s[(j * 4 + 0) * 100 + row] = w.x; A_s[(j * 4 + 1) * 100 + row] = w.y;
            A_s[(j * 4 + 2) * 100 + row] = w.z; A_s[(j * 4 + 3) * 100 + row] = w.w;
        }
#pragma unroll
        for (int f = tid; f < 1024; f += 256) {
            int r = f >> 5, c4 = f & 31;
            *(float4*)&B_s[r * 132 + c4 * 4] =
                *(const float4*)&vb[(size_t)(kc + r) * HWN + n0 + c4 * 4];
        }
        __syncthreads();
#pragma unroll
        for (int kk = 0; kk < 32; kk++) {
            float a6[6], bv[8];
            *(float2*)(a6 + 0) = *(const float2*)&A_s[kk * 100 + ot * 6 + 0];
            *(float2*)(a6 + 2) = *(const float2*)&A_s[kk * 100 + ot * 6 + 2];
            *(float2*)(a6 + 4) = *(const float2*)&A_s[kk * 100 + ot * 6 + 4];
            *(float4*)(bv + 0) = *(const float4*)&B_s[kk * 132 + pt * 4];
            *(float4*)(bv + 4) = *(const float4*)&B_s[kk * 132 + 64 + pt * 4];
#pragma unroll
            for (int i = 0; i < 6; i++)
#pragma unroll
                for (int j = 0; j < 8; j++) acc[i][j] = fmaf(a6[i], bv[j], acc[i][j]);
        }
    }
#pragma unroll
    for (int i = 0; i < 6; i++) {
        int o = o0 + ot * 6 + i;
        float bs = bias[o];
        float4 v0 = {acc[i][0] + bs, acc[i][1] + bs, acc[i][2] + bs, acc[i][3] + bs};
        float4 v1 = {acc[i][4] + bs, acc[i][5] + bs, acc[i][6] + bs, acc[i][7] + bs};
        *(float4*)&yb[(size_t)o * HWN + n0 + pt * 4] = v0;
        *(float4*)&yb[(size_t)o * HWN + n0 + 64 + pt * 4] = v1;
    }
}

// ============ K5 fallback: in-place y = M_b @ v + b_proj on d_out (proven R1 kernel) ============
__global__ __launch_bounds__(256) void k5_proj(float* __restrict__ vy, const float* __restrict__ M,
                                               const float* __restrict__ bias) {
    __shared__ float v_s[192][68];
    __shared__ float M_s[32][196];
    const int b = blockIdx.y;
    const int n0 = blockIdx.x * 64;
    const int tid = threadIdx.x;
    float* vb = vy + (size_t)b * DIMC * HWN;
#pragma unroll
    for (int f = tid; f < 3072; f += 256) {
        int row = f >> 4, q = f & 15;
        *(float4*)&v_s[row][q * 4] = *(const float4*)&vb[(size_t)row * HWN + n0 + q * 4];
    }
    const float* Mb = M + (size_t)b * DIMC * DIMC;
    const int pt = tid & 15, ot = tid >> 4;
    float acc[12][4];
#pragma unroll
    for (int i = 0; i < 12; i++)
#pragma unroll
        for (int j = 0; j < 4; j++) acc[i][j] = 0.f;

    for (int kc = 0; kc < DIMC; kc += 32) {
        __syncthreads();
#pragma unroll
        for (int f = tid; f < 1536; f += 256) {
            int row = f >> 3, j4 = f & 7;
            float4 w = *(const float4*)&Mb[row * DIMC + kc + j4 * 4];
            M_s[j4 * 4 + 0][row] = w.x; M_s[j4 * 4 + 1][row] = w.y;
            M_s[j4 * 4 + 2][row] = w.z; M_s[j4 * 4 + 3][row] = w.w;
        }
        __syncthreads();
#pragma unroll
        for (int kk = 0; kk < 32; kk++) {
            float a[12], bv[4];
            *(float4*)(a) = *(const float4*)&M_s[kk][ot * 12];
            *(float4*)(a + 4) = *(const float4*)&M_s[kk][ot * 12 + 4];
            *(float4*)(a + 8) = *(const float4*)&M_s[kk][ot * 12 + 8];
            *(float4*)bv = *(const float4*)&v_s[kc + kk][pt * 4];
#pragma unroll
            for (int i = 0; i < 12; i++)
#pragma unroll
                for (int j = 0; j < 4; j++) acc[i][j] = fmaf(a[i], bv[j], acc[i][j]);
        }
    }
#pragma unroll
    for (int i = 0; i < 12; i++) {
        int o = ot * 12 + i;
        float bs = bias[o];
        float4 w = {acc[i][0] + bs, acc[i][1] + bs, acc[i][2] + bs, acc[i][3] + bs};
        *(float4*)&vb[(size_t)o * HWN + n0 + pt * 4] = w;
    }
}

extern "C" void kernel_launch(void* const* d_in, const int* in_sizes, int n_in,
                              void* d_out, int out_size, void* d_ws, size_t ws_size,
                              hipStream_t stream) {
    const float* x     = (const float*)d_in[0];
    const float* wqkv  = (const float*)d_in[1];
    const float* bqkv  = (const float*)d_in[2];
    const float* wdw   = (const float*)d_in[3];
    const float* bdw   = (const float*)d_in[4];
    const float* wproj = (const float*)d_in[5];
    const float* bproj = (const float*)d_in[6];
    const float* temp  = (const float*)d_in[7];
    const float* a1    = (const float*)d_in[8];
    const float* a2    = (const float*)d_in[9];
    const float* a3    = (const float*)d_in[10];
    const float* a4    = (const float*)d_in[11];
    float* out = (float*)d_out;

    float* ws = (float*)d_ws;
    size_t o_qkv  = 0;                                // 576*16384
    size_t o_part = o_qkv + (size_t)C3 * HWN;         // 64*64*624
    size_t o_G    = o_part + (size_t)64 * 64 * 624;   // 64*576
    size_t o_nq   = o_G + (size_t)64 * 576;
    size_t o_nk   = o_nq + (size_t)NBATCH * DIMC;
    size_t o_A    = o_nk + (size_t)NBATCH * DIMC;
    size_t o_M    = o_A + (size_t)64 * 576;
    size_t o_v    = o_M + (size_t)NBATCH * DIMC * DIMC;
    size_t total_fast = o_v + (size_t)NBATCH * DIMC * HWN;  // ~150 MB
    float* qkv_raw = ws + o_qkv;
    float* part    = ws + o_part;
    float* G       = ws + o_G;
    float* nq      = ws + o_nq;
    float* nk      = ws + o_nk;
    float* Aeff    = ws + o_A;
    float* M       = ws + o_M;

    const bool fast = ws_size >= total_fast * sizeof(float);
    float* vbuf = fast ? (ws + o_v) : out;

    for (int b = 0; b < NBATCH; b++) {
        k1_conv1x1<<<dim3(128, 6), 256, 0, stream>>>(x, wqkv, bqkv, qkv_raw, b);
        k2_dw<<<dim3(64, 8), 256, 0, stream>>>(qkv_raw, wdw, bdw, vbuf, part, b);
    }
    k3_reduce<<<64, 256, 0, stream>>>(part, G, nq, nk);
    k4a_attn<<<dim3(8, 8), 64, 0, stream>>>(G, nq, nk, temp, a1, a2, a3, a4, Aeff);
    k4b_mmat<<<dim3(8, 6), 256, 0, stream>>>(wproj, Aeff, M);
    if (fast) {
        k5_fast<<<dim3(128, 2, 8), 256, 0, stream>>>(vbuf, M, bproj, out);
    } else {
        k5_proj<<<dim3(256, 8), 256, 0, stream>>>(out, M, bproj);
    }
}

// Round 3
// 834.461 us; speedup vs baseline: 1.7958x; 1.0733x over previous
//
#include <hip/hip_runtime.h>
#include <math.h>

#define DIMC 192
#define C3 576
#define NHEADS 8
#define CDh 24
#define HWN 16384
#define WIDTH 128
#define NBATCH 8

// ============ K1: conv1x1: qkv[z][576][16384] = W(576x192) @ x_b + b ============
// grid (128 n-tiles, 6 m-tiles, NZ), block 256. Tile 96(M)x128(N), thread 6x8.
__global__ __launch_bounds__(256) void k1_conv1x1(const float* __restrict__ x,
                                                  const float* __restrict__ W,
                                                  const float* __restrict__ bias,
                                                  float* __restrict__ out0,
                                                  long out_zstride, int b0) {
    __shared__ float A_s[32 * 100];
    __shared__ float B_s[32 * 132];
    const int b = b0 + blockIdx.z;
    const float* xb = x + (size_t)b * DIMC * HWN;
    float* out = out0 + (size_t)blockIdx.z * out_zstride;
    const int n0 = blockIdx.x * 128;
    const int o0 = blockIdx.y * 96;
    const int tid = threadIdx.x;
    const int pt = tid & 15, ot = tid >> 4;
    float acc[6][8];
#pragma unroll
    for (int i = 0; i < 6; i++)
#pragma unroll
        for (int j = 0; j < 8; j++) acc[i][j] = 0.f;

    for (int kc = 0; kc < DIMC; kc += 32) {
        __syncthreads();
#pragma unroll
        for (int f = tid; f < 768; f += 256) {
            int row = f >> 3, j = f & 7;
            float4 v = *(const float4*)&W[(size_t)(o0 + row) * DIMC + kc + j * 4];
            A_s[(j * 4 + 0) * 100 + row] = v.x; A_s[(j * 4 + 1) * 100 + row] = v.y;
            A_s[(j * 4 + 2) * 100 + row] = v.z; A_s[(j * 4 + 3) * 100 + row] = v.w;
        }
#pragma unroll
        for (int f = tid; f < 1024; f += 256) {
            int r = f >> 5, c4 = f & 31;
            *(float4*)&B_s[r * 132 + c4 * 4] =
                *(const float4*)&xb[(size_t)(kc + r) * HWN + n0 + c4 * 4];
        }
        __syncthreads();
#pragma unroll
        for (int kk = 0; kk < 32; kk++) {
            float a6[6], bv[8];
            *(float2*)(a6 + 0) = *(const float2*)&A_s[kk * 100 + ot * 6 + 0];
            *(float2*)(a6 + 2) = *(const float2*)&A_s[kk * 100 + ot * 6 + 2];
            *(float2*)(a6 + 4) = *(const float2*)&A_s[kk * 100 + ot * 6 + 4];
            *(float4*)(bv + 0) = *(const float4*)&B_s[kk * 132 + pt * 4];
            *(float4*)(bv + 4) = *(const float4*)&B_s[kk * 132 + 64 + pt * 4];
#pragma unroll
            for (int i = 0; i < 6; i++)
#pragma unroll
                for (int j = 0; j < 8; j++) acc[i][j] = fmaf(a6[i], bv[j], acc[i][j]);
        }
    }
#pragma unroll
    for (int i = 0; i < 6; i++) {
        int o = o0 + ot * 6 + i;
        float bs = bias[o];
        float4 v0 = {acc[i][0] + bs, acc[i][1] + bs, acc[i][2] + bs, acc[i][3] + bs};
        float4 v1 = {acc[i][4] + bs, acc[i][5] + bs, acc[i][6] + bs, acc[i][7] + bs};
        *(float4*)&out[(size_t)o * HWN + n0 + pt * 4] = v0;
        *(float4*)&out[(size_t)o * HWN + n0 + 64 + pt * 4] = v1;
    }
}

// ============ K2: depthwise 3x3 + Gram/sumsq partials (fp32 end-to-end) ============
// grid (32 stripes of 4 rows, 8 heads, NZ), block 1024 (16 waves), 1 block/CU.
// LDS: stage[8ch][6rows][132] 25.3KB + qks[48][520] fp32 99.8KB = 125.2KB.
__global__ __launch_bounds__(1024, 4) void k2_dw(const float* __restrict__ qkv0,
                                                 long qkv_zstride,
                                                 const float* __restrict__ wdw,
                                                 const float* __restrict__ bdw,
                                                 float* __restrict__ vout,
                                                 float* __restrict__ part, int b0) {
    __shared__ float stage[6336];       // [8][6][132]
    __shared__ float qks[48 * 520];     // [qk ch][512 px + pad], fp32
    const int b = b0 + blockIdx.z;
    const float* qkv = qkv0 + (size_t)blockIdx.z * qkv_zstride;
    const int stripe = blockIdx.x, h = blockIdx.y;
    const int tid = threadIdx.x;
    const int r0 = stripe * 4;

    const int col4 = (tid & 31) * 4;
    const int orow = (tid >> 5) & 3;
    const int cc = tid >> 7;  // 0..7

    for (int chunk = 0; chunk < 9; chunk++) {
        const int g = chunk / 3, cb = (chunk % 3) * 8;
        __syncthreads();
        // stage 8 ch x 6 rows x 128 cols (1536 float4)
#pragma unroll
        for (int f = tid; f < 1536; f += 1024) {
            int fc = f / 192, rem = f - fc * 192;
            int rl = rem >> 5, c4 = rem & 31;
            int gr = r0 - 1 + rl;
            int ch = g * DIMC + h * CDh + cb + fc;
            float4 v = make_float4(0.f, 0.f, 0.f, 0.f);
            if (gr >= 0 && gr < 128)
                v = *(const float4*)&qkv[(size_t)ch * HWN + gr * WIDTH + c4 * 4];
            *(float4*)&stage[(fc * 6 + rl) * 132 + c4 * 4] = v;
        }
        __syncthreads();
        {
            const int ch = g * DIMC + h * CDh + cb + cc;
            float wr[9];
#pragma unroll
            for (int t = 0; t < 9; t++) wr[t] = wdw[ch * 9 + t];
            float bsv = bdw[ch];
            float a0 = bsv, a1 = bsv, a2 = bsv, a3 = bsv;
#pragma unroll
            for (int dr = 0; dr < 3; dr++) {
                const float* row = &stage[(cc * 6 + orow + dr) * 132];
                float left = (col4 > 0) ? row[col4 - 1] : 0.f;
                float4 c = *(const float4*)&row[col4];
                float right = (col4 < 124) ? row[col4 + 4] : 0.f;
                float wA = wr[dr * 3 + 0], wB = wr[dr * 3 + 1], wC = wr[dr * 3 + 2];
                a0 = fmaf(left, wA, fmaf(c.x, wB, fmaf(c.y, wC, a0)));
                a1 = fmaf(c.x, wA, fmaf(c.y, wB, fmaf(c.z, wC, a1)));
                a2 = fmaf(c.y, wA, fmaf(c.z, wB, fmaf(c.w, wC, a2)));
                a3 = fmaf(c.z, wA, fmaf(c.w, wB, fmaf(right, wC, a3)));
            }
            float4 o4 = {a0, a1, a2, a3};
            if (g == 2) {
                *(float4*)&vout[((size_t)b * DIMC + h * CDh + cb + cc) * HWN +
                                (size_t)(r0 + orow) * WIDTH + col4] = o4;
            } else {
                *(float4*)&qks[(g * CDh + cb + cc) * 520 + orow * 128 + col4] = o4;
            }
        }
    }
    __syncthreads();  // qks complete

    // Gram: thread = (tc 4, td 4, tp 64 of 8 px); 6x6 register tile
    const int tc = tid & 3, td = (tid >> 2) & 3, tp = tid >> 4;
    float ga[6][6];
#pragma unroll
    for (int i = 0; i < 6; i++)
#pragma unroll
        for (int j = 0; j < 6; j++) ga[i][j] = 0.f;
#pragma unroll
    for (int s = 0; s < 2; s++) {
        int px = tp * 8 + s * 4;
        float4 qv[6], kv[6];
#pragma unroll
        for (int i = 0; i < 6; i++) qv[i] = *(const float4*)&qks[(tc * 6 + i) * 520 + px];
#pragma unroll
        for (int j = 0; j < 6; j++) kv[j] = *(const float4*)&qks[(24 + td * 6 + j) * 520 + px];
#pragma unroll
        for (int i = 0; i < 6; i++)
#pragma unroll
            for (int j = 0; j < 6; j++) {
                ga[i][j] = fmaf(qv[i].x, kv[j].x, ga[i][j]);
                ga[i][j] = fmaf(qv[i].y, kv[j].y, ga[i][j]);
                ga[i][j] = fmaf(qv[i].z, kv[j].z, ga[i][j]);
                ga[i][j] = fmaf(qv[i].w, kv[j].w, ga[i][j]);
            }
    }
    // butterfly over tp-within-wave (lane bits 4,5)
#pragma unroll
    for (int i = 0; i < 6; i++)
#pragma unroll
        for (int j = 0; j < 6; j++) {
            float v = ga[i][j];
            v += __shfl_xor(v, 16, 64);
            v += __shfl_xor(v, 32, 64);
            ga[i][j] = v;
        }
    // norms: tid<768: ch = tid%48, pg = tid/48 (16 groups of 32 px)
    float nv = 0.f;
    int nch = 0, npg = 0;
    if (tid < 768) {
        npg = tid / 48;
        nch = tid - npg * 48;
#pragma unroll
        for (int s = 0; s < 8; s++) {
            float4 v = *(const float4*)&qks[nch * 520 + npg * 32 + s * 4];
            nv = fmaf(v.x, v.x, nv);
            nv = fmaf(v.y, v.y, nv);
            nv = fmaf(v.z, v.z, nv);
            nv = fmaf(v.w, v.w, nv);
        }
    }
    __syncthreads();  // all qks reads done; safe to overlay gscr
    float* gscr = qks;  // [16][624]
    const int wave = tid >> 6;
    if ((tid & 63) < 16) {
#pragma unroll
        for (int i = 0; i < 6; i++)
#pragma unroll
            for (int j = 0; j < 6; j++)
                gscr[wave * 624 + (tc * 6 + i) * 24 + (td * 6 + j)] = ga[i][j];
    }
    if (tid < 768) gscr[npg * 624 + 576 + nch] = nv;
    __syncthreads();
    if (tid < 624) {
        float s = 0.f;
#pragma unroll
        for (int w2 = 0; w2 < 16; w2++) s += gscr[w2 * 624 + tid];
        part[((size_t)(b * NHEADS + h) * 624 + tid) * 32 + stripe] = s;
    }
}

// ============ K3: reduce stripe partials, coalesced (fixed order -> deterministic) ============
// grid 64 (bh), block 256 (4 waves). part layout [bh][624][32].
__global__ void k3_reduce(const float* __restrict__ part, float* __restrict__ G,
                          float* __restrict__ nq, float* __restrict__ nk) {
    int bh = blockIdx.x;
    int b = bh >> 3, h = bh & 7;
    int tid = threadIdx.x;
    int lane = tid & 63, wave = tid >> 6;
    int half = lane >> 5, sl = lane & 31;
    for (int tp = wave; tp < 312; tp += 4) {
        int ti = tp * 2 + half;
        float v = part[((size_t)bh * 624 + ti) * 32 + sl];
        v += __shfl_xor(v, 1, 64);
        v += __shfl_xor(v, 2, 64);
        v += __shfl_xor(v, 4, 64);
        v += __shfl_xor(v, 8, 64);
        v += __shfl_xor(v, 16, 64);
        if (sl == 0) {
            if (ti < 576) G[bh * 576 + ti] = v;
            else if (ti < 600) nq[b * DIMC + h * CDh + (ti - 576)] = v;
            else nk[b * DIMC + h * CDh + (ti - 600)] = v;
        }
    }
}

// ============ K4a: attn + 4 top-k sparse softmaxes -> A_eff ============
__global__ void k4a_attn(const float* __restrict__ G, const float* __restrict__ nq,
                         const float* __restrict__ nk, const float* __restrict__ temp,
                         const float* __restrict__ a1, const float* __restrict__ a2,
                         const float* __restrict__ a3, const float* __restrict__ a4,
                         float* __restrict__ Aeff) {
    int h = blockIdx.x, b = blockIdx.y;
    int bh = b * NHEADS + h;
    int r = threadIdx.x;
    if (r >= CDh) return;
    float t = temp[h];
    float aw[4] = {a1[0], a2[0], a3[0], a4[0]};
    const int kks[4] = {12, 16, 18, 19};
    float qn = fmaxf(sqrtf(nq[b * DIMC + h * CDh + r]), 1e-12f);
    float av[24];
    for (int d = 0; d < 24; d++) {
        float kn = fmaxf(sqrtf(nk[b * DIMC + h * CDh + d]), 1e-12f);
        av[d] = G[bh * 576 + r * 24 + d] / (qn * kn) * t;
    }
    int rank[24];
    float m = -1e30f;
    for (int d = 0; d < 24; d++) {
        int rk = 0;
        for (int e = 0; e < 24; e++)
            rk += (av[e] > av[d]) || (av[e] == av[d] && e < d);
        rank[d] = rk;
        m = fmaxf(m, av[d]);
    }
    float ex[24], outv[24];
    for (int d = 0; d < 24; d++) { ex[d] = expf(av[d] - m); outv[d] = 0.f; }
    for (int i = 0; i < 4; i++) {
        float Z = 0.f;
        for (int d = 0; d < 24; d++) if (rank[d] < kks[i]) Z += ex[d];
        float inv = aw[i] / Z;
        for (int d = 0; d < 24; d++) if (rank[d] < kks[i]) outv[d] += ex[d] * inv;
    }
    for (int d = 0; d < 24; d++) Aeff[(bh * 24 + r) * 24 + d] = outv[d];
}

// ============ K4b: M_b = W_proj @ blockdiag(A_eff) ============
__global__ void k4b_mmat(const float* __restrict__ Wp, const float* __restrict__ Aeff,
                         float* __restrict__ M) {
    int b = blockIdx.x;
    int e0 = blockIdx.y * 6144;
    for (int e = e0 + threadIdx.x; e < e0 + 6144; e += 256) {
        int o = e / DIMC, j = e % DIMC;
        int h = j / CDh, d = j % CDh;
        const float* wrow = Wp + o * DIMC + h * CDh;
        const float* acol = Aeff + (size_t)((b * NHEADS + h) * CDh) * CDh + d;
        float s = 0.f;
        for (int c = 0; c < CDh; c++) s = fmaf(wrow[c], acol[c * CDh], s);
        M[((size_t)b * DIMC + o) * DIMC + j] = s;
    }
}

// ============ K5 fast: y = M_b @ v + b_proj (v in ws) ============
__global__ __launch_bounds__(256) void k5_fast(const float* __restrict__ v,
                                               const float* __restrict__ M,
                                               const float* __restrict__ bias,
                                               float* __restrict__ y) {
    __shared__ float A_s[32 * 100];
    __shared__ float B_s[32 * 132];
    const int b = blockIdx.z;
    const float* vb = v + (size_t)b * DIMC * HWN;
    const float* Mb = M + (size_t)b * DIMC * DIMC;
    float* yb = y + (size_t)b * DIMC * HWN;
    const int n0 = blockIdx.x * 128;
    const int o0 = blockIdx.y * 96;
    const int tid = threadIdx.x;
    const int pt = tid & 15, ot = tid >> 4;
    float acc[6][8];
#pragma unroll
    for (int i = 0; i < 6; i++)
#pragma unroll
        for (int j = 0; j < 8; j++) acc[i][j] = 0.f;

    for (int kc = 0; kc < DIMC; kc += 32) {
        __syncthreads();
#pragma unroll
        for (int f = tid; f < 768; f += 256) {
            int row = f >> 3, j = f & 7;
            float4 w = *(const float4*)&Mb[(size_t)(o0 + row) * DIMC + kc + j * 4];
            A_s[(j * 4 + 0) * 100 + row] = w.x; A_s[(j * 4 + 1) * 100 + row] = w.y;
            A_s[(j * 4 + 2) * 100 + row] = w.z; A_s[(j * 4 + 3) * 100 + row] = w.w;
        }
#pragma unroll
        for (int f = tid; f < 1024; f += 256) {
            int r = f >> 5, c4 = f & 31;
            *(float4*)&B_s[r * 132 + c4 * 4] =
                *(const float4*)&vb[(size_t)(kc + r) * HWN + n0 + c4 * 4];
        }
        __syncthreads();
#pragma unroll
        for (int kk = 0; kk < 32; kk++) {
            float a6[6], bv[8];
            *(float2*)(a6 + 0) = *(const float2*)&A_s[kk * 100 + ot * 6 + 0];
            *(float2*)(a6 + 2) = *(const float2*)&A_s[kk * 100 + ot * 6 + 2];
            *(float2*)(a6 + 4) = *(const float2*)&A_s[kk * 100 + ot * 6 + 4];
            *(float4*)(bv + 0) = *(const float4*)&B_s[kk * 132 + pt * 4];
            *(float4*)(bv + 4) = *(const float4*)&B_s[kk * 132 + 64 + pt * 4];
#pragma unroll
            for (int i = 0; i < 6; i++)
#pragma unroll
                for (int j = 0; j < 8; j++) acc[i][j] = fmaf(a6[i], bv[j], acc[i][j]);
        }
    }
#pragma unroll
    for (int i = 0; i < 6; i++) {
        int o = o0 + ot * 6 + i;
        float bs = bias[o];
        float4 v0 = {acc[i][0] + bs, acc[i][1] + bs, acc[i][2] + bs, acc[i][3] + bs};
        float4 v1 = {acc[i][4] + bs, acc[i][5] + bs, acc[i][6] + bs, acc[i][7] + bs};
        *(float4*)&yb[(size_t)o * HWN + n0 + pt * 4] = v0;
        *(float4*)&yb[(size_t)o * HWN + n0 + 64 + pt * 4] = v1;
    }
}

// ============ K5 fallback: in-place on d_out ============
__global__ __launch_bounds__(256) void k5_proj(float* __restrict__ vy, const float* __restrict__ M,
                                               const float* __restrict__ bias) {
    __shared__ float v_s[192][68];
    __shared__ float M_s[32][196];
    const int b = blockIdx.y;
    const int n0 = blockIdx.x * 64;
    const int tid = threadIdx.x;
    float* vb = vy + (size_t)b * DIMC * HWN;
#pragma unroll
    for (int f = tid; f < 3072; f += 256) {
        int row = f >> 4, q = f & 15;
        *(float4*)&v_s[row][q * 4] = *(const float4*)&vb[(size_t)row * HWN + n0 + q * 4];
    }
    const float* Mb = M + (size_t)b * DIMC * DIMC;
    const int pt = tid & 15, ot = tid >> 4;
    float acc[12][4];
#pragma unroll
    for (int i = 0; i < 12; i++)
#pragma unroll
        for (int j = 0; j < 4; j++) acc[i][j] = 0.f;

    for (int kc = 0; kc < DIMC; kc += 32) {
        __syncthreads();
#pragma unroll
        for (int f = tid; f < 1536; f += 256) {
            int row = f >> 3, j4 = f & 7;
            float4 w = *(const float4*)&Mb[row * DIMC + kc + j4 * 4];
            M_s[j4 * 4 + 0][row] = w.x; M_s[j4 * 4 + 1][row] = w.y;
            M_s[j4 * 4 + 2][row] = w.z; M_s[j4 * 4 + 3][row] = w.w;
        }
        __syncthreads();
#pragma unroll
        for (int kk = 0; kk < 32; kk++) {
            float a[12], bv[4];
            *(float4*)(a) = *(const float4*)&M_s[kk][ot * 12];
            *(float4*)(a + 4) = *(const float4*)&M_s[kk][ot * 12 + 4];
            *(float4*)(a + 8) = *(const float4*)&M_s[kk][ot * 12 + 8];
            *(float4*)bv = *(const float4*)&v_s[kc + kk][pt * 4];
#pragma unroll
            for (int i = 0; i < 12; i++)
#pragma unroll
                for (int j = 0; j < 4; j++) acc[i][j] = fmaf(a[i], bv[j], acc[i][j]);
        }
    }
#pragma unroll
    for (int i = 0; i < 12; i++) {
        int o = ot * 12 + i;
        float bs = bias[o];
        float4 w = {acc[i][0] + bs, acc[i][1] + bs, acc[i][2] + bs, acc[i][3] + bs};
        *(float4*)&vb[(size_t)o * HWN + n0 + pt * 4] = w;
    }
}

extern "C" void kernel_launch(void* const* d_in, const int* in_sizes, int n_in,
                              void* d_out, int out_size, void* d_ws, size_t ws_size,
                              hipStream_t stream) {
    const float* x     = (const float*)d_in[0];
    const float* wqkv  = (const float*)d_in[1];
    const float* bqkv  = (const float*)d_in[2];
    const float* wdw   = (const float*)d_in[3];
    const float* bdw   = (const float*)d_in[4];
    const float* wproj = (const float*)d_in[5];
    const float* bproj = (const float*)d_in[6];
    const float* temp  = (const float*)d_in[7];
    const float* a1    = (const float*)d_in[8];
    const float* a2    = (const float*)d_in[9];
    const float* a3    = (const float*)d_in[10];
    const float* a4    = (const float*)d_in[11];
    float* out = (float*)d_out;

    float* ws = (float*)d_ws;
    const size_t fl_part = (size_t)64 * 624 * 32;          // 1,277,952
    size_t o_part = 0;
    size_t o_G    = o_part + fl_part;                      // 64*576
    size_t o_nq   = o_G + (size_t)64 * 576;
    size_t o_nk   = o_nq + (size_t)NBATCH * DIMC;
    size_t o_A    = o_nk + (size_t)NBATCH * DIMC;          // 64*576
    size_t o_M    = o_A + (size_t)64 * 576;                // 8*192*192
    size_t o_v    = o_M + (size_t)NBATCH * DIMC * DIMC;    // 8*192*16384
    size_t o_qkv  = o_v + (size_t)NBATCH * DIMC * HWN;
    size_t fl_loop    = o_qkv + (size_t)C3 * HWN;          // ~145 MB
    size_t fl_batched = o_qkv + (size_t)NBATCH * C3 * HWN; // ~409 MB

    float* part = ws + o_part;
    float* G    = ws + o_G;
    float* nq   = ws + o_nq;
    float* nk   = ws + o_nk;
    float* Aeff = ws + o_A;
    float* M    = ws + o_M;
    float* qkv  = ws + o_qkv;

    const bool batched  = ws_size >= fl_batched * sizeof(float);
    const bool loopfast = ws_size >= fl_loop * sizeof(float);
    float* vbuf = loopfast ? (ws + o_v) : out;
    const long zs = (long)C3 * HWN;

    if (batched) {
        k1_conv1x1<<<dim3(128, 6, 8), 256, 0, stream>>>(x, wqkv, bqkv, qkv, zs, 0);
        k2_dw<<<dim3(32, 8, 8), 1024, 0, stream>>>(qkv, zs, wdw, bdw, vbuf, part, 0);
    } else {
        // tiny-ws tier: place qkv right after M (no v region), v -> d_out
        if (!loopfast) qkv = ws + o_v;
        for (int b = 0; b < NBATCH; b++) {
            k1_conv1x1<<<dim3(128, 6, 1), 256, 0, stream>>>(x, wqkv, bqkv, qkv, 0, b);
            k2_dw<<<dim3(32, 8, 1), 1024, 0, stream>>>(qkv, 0, wdw, bdw, vbuf, part, b);
        }
    }
    k3_reduce<<<64, 256, 0, stream>>>(part, G, nq, nk);
    k4a_attn<<<dim3(8, 8), 64, 0, stream>>>(G, nq, nk, temp, a1, a2, a3, a4, Aeff);
    k4b_mmat<<<dim3(8, 6), 256, 0, stream>>>(wproj, Aeff, M);
    if (loopfast) {
        k5_fast<<<dim3(128, 2, 8), 256, 0, stream>>>(vbuf, M, bproj, out);
    } else {
        k5_proj<<<dim3(256, 8), 256, 0, stream>>>(out, M, bproj);
    }
}

// Round 4
// 691.204 us; speedup vs baseline: 2.1680x; 1.2073x over previous
//
#include <hip/hip_runtime.h>
#include <math.h>

#define DIMC 192
#define C3 576
#define NHEADS 8
#define CDh 24
#define HWN 16384
#define WIDTH 128
#define NBATCH 8

typedef __attribute__((ext_vector_type(8))) short short8;
typedef __attribute__((ext_vector_type(4))) float f32x4;

__device__ __forceinline__ ushort f2bf(float f) {
    uint u = __float_as_uint(f);
    u += 0x7fff + ((u >> 16) & 1);
    return (ushort)(u >> 16);
}
__device__ __forceinline__ float bf2f(ushort h) {
    return __uint_as_float(((uint)h) << 16);
}
union H16 { ushort u; _Float16 h; };
__device__ __forceinline__ ushort f2h_bits(float f) { H16 x; x.h = (_Float16)f; return x.u; }
__device__ __forceinline__ float h2f_bits(ushort u) { H16 x; x.u = u; return (float)x.h; }
union S8U4 { short8 s; uint u[4]; };

// ============ K0: split W_qkv -> bf16 hi/lo ============
__global__ void k0_prep(const float* __restrict__ W, ushort* __restrict__ Wh,
                        ushort* __restrict__ Wl, int n) {
    int i = blockIdx.x * 256 + threadIdx.x;
    if (i < n) {
        float w = W[i];
        ushort h = f2bf(w);
        Wh[i] = h;
        Wl[i] = f2bf(w - bf2f(h));
    }
}

// ============ K1m: conv1x1 via split-bf16 MFMA ============
// grid (256 n-tiles of 64, 1, NZ), block 256 (4 waves; wave = 144 rows x 64 cols).
// Writes q,k (rows 0..383) as fp16 to qkb; v (rows 384..575) fp32 to vraw.
__global__ __launch_bounds__(256) void k1m(const float* __restrict__ x,
                                           const ushort* __restrict__ Wh,
                                           const ushort* __restrict__ Wl,
                                           const float* __restrict__ bias,
                                           ushort* __restrict__ qkb, long qkb_zs,
                                           float* __restrict__ vraw, long vraw_zs,
                                           int b0) {
    __shared__ float Bs[32 * 68];  // [k][n], stride 68 (272B, 16B-aligned rows)
    const int z = blockIdx.z;
    const float* xb = x + (size_t)(b0 + z) * DIMC * HWN;
    ushort* qkz = qkb + (size_t)z * qkb_zs;
    float* vz = vraw + (size_t)z * vraw_zs;
    const int n0 = blockIdx.x * 64;
    const int tid = threadIdx.x;
    const int wid = tid >> 6, lane = tid & 63;
    const int lr = lane & 15, lk = lane >> 4;
    const int mb = wid * 144;
    f32x4 acc[9][4];
#pragma unroll
    for (int i = 0; i < 9; i++)
#pragma unroll
        for (int j = 0; j < 4; j++) acc[i][j] = (f32x4)0.f;

    for (int kc = 0; kc < DIMC; kc += 32) {
        __syncthreads();
        // stage x[kc..+32][n0..+64] fp32 (512 float4, 2/thread, coalesced)
#pragma unroll
        for (int it = 0; it < 2; it++) {
            int f4 = tid + it * 256;
            int r = f4 >> 4, c4 = (f4 & 15) * 4;
            *(f32x4*)&Bs[r * 68 + c4] =
                *(const f32x4*)&xb[(size_t)(kc + r) * HWN + n0 + c4];
        }
        __syncthreads();
        // per-wave: build B fragments hi/lo (col = j*16+lr, k = lk*8 + 0..7)
        short8 bh[4], bl[4];
#pragma unroll
        for (int j = 0; j < 4; j++) {
            int n = j * 16 + lr;
            S8U4 H, L;
#pragma unroll
            for (int p = 0; p < 4; p++) {
                float v0 = Bs[(lk * 8 + 2 * p) * 68 + n];
                float v1 = Bs[(lk * 8 + 2 * p + 1) * 68 + n];
                ushort h0 = f2bf(v0), h1 = f2bf(v1);
                ushort l0 = f2bf(v0 - bf2f(h0)), l1 = f2bf(v1 - bf2f(h1));
                H.u[p] = (uint)h0 | ((uint)h1 << 16);
                L.u[p] = (uint)l0 | ((uint)l1 << 16);
            }
            bh[j] = H.s; bl[j] = L.s;
        }
#pragma unroll
        for (int i = 0; i < 9; i++) {
            int row = mb + i * 16 + lr;
            const short8 ah = *(const short8*)&Wh[(size_t)row * DIMC + kc + lk * 8];
            const short8 al = *(const short8*)&Wl[(size_t)row * DIMC + kc + lk * 8];
#pragma unroll
            for (int j = 0; j < 4; j++) {
                acc[i][j] = __builtin_amdgcn_mfma_f32_16x16x32_bf16(ah, bh[j], acc[i][j], 0, 0, 0);
                acc[i][j] = __builtin_amdgcn_mfma_f32_16x16x32_bf16(ah, bl[j], acc[i][j], 0, 0, 0);
                acc[i][j] = __builtin_amdgcn_mfma_f32_16x16x32_bf16(al, bh[j], acc[i][j], 0, 0, 0);
            }
        }
    }
    // epilogue: D row = (lane>>4)*4 + reg, col = lane&15 (frag-aligned: no 384-straddle)
#pragma unroll
    for (int i = 0; i < 9; i++) {
        int rbase = mb + i * 16 + lk * 4;
#pragma unroll
        for (int r = 0; r < 4; r++) {
            int row = rbase + r;
            float bsv = bias[row];
#pragma unroll
            for (int j = 0; j < 4; j++) {
                int col = n0 + j * 16 + lr;
                float val = acc[i][j][r] + bsv;
                if (row < 384) qkz[(size_t)row * HWN + col] = f2h_bits(val);
                else vz[(size_t)(row - 384) * HWN + col] = val;
            }
        }
    }
}

// ============ K2: depthwise 3x3 + Gram/sumsq partials (q,k fp16 in; fp32 internal) ============
// grid (32 stripes of 4 rows, 8 heads, NZ), block 1024.
__global__ __launch_bounds__(1024, 4) void k2_dw(const ushort* __restrict__ qkb, long qkb_zs,
                                                 const float* __restrict__ vraw, long vraw_zs,
                                                 const float* __restrict__ wdw,
                                                 const float* __restrict__ bdw,
                                                 float* __restrict__ vout,
                                                 float* __restrict__ part, int b0) {
    __shared__ float stage[6336];       // [8][6][132]
    __shared__ float qks[48 * 520];     // [qk ch][512 px + pad], fp32
    const int b = b0 + blockIdx.z;
    const ushort* qkz = qkb + (size_t)blockIdx.z * qkb_zs;
    const float* vz = vraw + (size_t)blockIdx.z * vraw_zs;
    const int stripe = blockIdx.x, h = blockIdx.y;
    const int tid = threadIdx.x;
    const int r0 = stripe * 4;

    const int col4 = (tid & 31) * 4;
    const int orow = (tid >> 5) & 3;
    const int cc = tid >> 7;  // 0..7

    for (int chunk = 0; chunk < 9; chunk++) {
        const int g = chunk / 3, cb = (chunk % 3) * 8;
        __syncthreads();
        if (g < 2) {
#pragma unroll
            for (int f = tid; f < 1536; f += 1024) {
                int fc = f / 192, rem = f - fc * 192;
                int rl = rem >> 5, c4 = rem & 31;
                int gr = r0 - 1 + rl;
                int ch = g * DIMC + h * CDh + cb + fc;
                float4 v = make_float4(0.f, 0.f, 0.f, 0.f);
                if (gr >= 0 && gr < 128) {
                    uint2 u = *(const uint2*)&qkz[(size_t)ch * HWN + gr * WIDTH + c4 * 4];
                    v.x = h2f_bits((ushort)(u.x & 0xffff));
                    v.y = h2f_bits((ushort)(u.x >> 16));
                    v.z = h2f_bits((ushort)(u.y & 0xffff));
                    v.w = h2f_bits((ushort)(u.y >> 16));
                }
                *(float4*)&stage[(fc * 6 + rl) * 132 + c4 * 4] = v;
            }
        } else {
#pragma unroll
            for (int f = tid; f < 1536; f += 1024) {
                int fc = f / 192, rem = f - fc * 192;
                int rl = rem >> 5, c4 = rem & 31;
                int gr = r0 - 1 + rl;
                int ch = h * CDh + cb + fc;
                float4 v = make_float4(0.f, 0.f, 0.f, 0.f);
                if (gr >= 0 && gr < 128)
                    v = *(const float4*)&vz[(size_t)ch * HWN + gr * WIDTH + c4 * 4];
                *(float4*)&stage[(fc * 6 + rl) * 132 + c4 * 4] = v;
            }
        }
        __syncthreads();
        {
            const int ch = g * DIMC + h * CDh + cb + cc;
            float wr[9];
#pragma unroll
            for (int t = 0; t < 9; t++) wr[t] = wdw[ch * 9 + t];
            float bsv = bdw[ch];
            float a0 = bsv, a1 = bsv, a2 = bsv, a3 = bsv;
#pragma unroll
            for (int dr = 0; dr < 3; dr++) {
                const float* row = &stage[(cc * 6 + orow + dr) * 132];
                float left = (col4 > 0) ? row[col4 - 1] : 0.f;
                float4 c = *(const float4*)&row[col4];
                float right = (col4 < 124) ? row[col4 + 4] : 0.f;
                float wA = wr[dr * 3 + 0], wB = wr[dr * 3 + 1], wC = wr[dr * 3 + 2];
                a0 = fmaf(left, wA, fmaf(c.x, wB, fmaf(c.y, wC, a0)));
                a1 = fmaf(c.x, wA, fmaf(c.y, wB, fmaf(c.z, wC, a1)));
                a2 = fmaf(c.y, wA, fmaf(c.z, wB, fmaf(c.w, wC, a2)));
                a3 = fmaf(c.z, wA, fmaf(c.w, wB, fmaf(right, wC, a3)));
            }
            float4 o4 = {a0, a1, a2, a3};
            if (g == 2) {
                *(float4*)&vout[((size_t)b * DIMC + h * CDh + cb + cc) * HWN +
                                (size_t)(r0 + orow) * WIDTH + col4] = o4;
            } else {
                *(float4*)&qks[(g * CDh + cb + cc) * 520 + orow * 128 + col4] = o4;
            }
        }
    }
    __syncthreads();  // qks complete

    // Gram: thread = (tc 4, td 4, tp 64 of 8 px); 6x6 register tile
    const int tc = tid & 3, td = (tid >> 2) & 3, tp = tid >> 4;
    float ga[6][6];
#pragma unroll
    for (int i = 0; i < 6; i++)
#pragma unroll
        for (int j = 0; j < 6; j++) ga[i][j] = 0.f;
#pragma unroll
    for (int s = 0; s < 2; s++) {
        int px = tp * 8 + s * 4;
        f32x4 qv[6], kv[6];
#pragma unroll
        for (int i = 0; i < 6; i++) qv[i] = *(const f32x4*)&qks[(tc * 6 + i) * 520 + px];
#pragma unroll
        for (int j = 0; j < 6; j++) kv[j] = *(const f32x4*)&qks[(24 + td * 6 + j) * 520 + px];
#pragma unroll
        for (int i = 0; i < 6; i++)
#pragma unroll
            for (int j = 0; j < 6; j++) {
                ga[i][j] = fmaf(qv[i][0], kv[j][0], ga[i][j]);
                ga[i][j] = fmaf(qv[i][1], kv[j][1], ga[i][j]);
                ga[i][j] = fmaf(qv[i][2], kv[j][2], ga[i][j]);
                ga[i][j] = fmaf(qv[i][3], kv[j][3], ga[i][j]);
            }
    }
#pragma unroll
    for (int i = 0; i < 6; i++)
#pragma unroll
        for (int j = 0; j < 6; j++) {
            float v = ga[i][j];
            v += __shfl_xor(v, 16, 64);
            v += __shfl_xor(v, 32, 64);
            ga[i][j] = v;
        }
    float nv = 0.f;
    int nch = 0, npg = 0;
    if (tid < 768) {
        npg = tid / 48;
        nch = tid - npg * 48;
#pragma unroll
        for (int s = 0; s < 8; s++) {
            f32x4 v = *(const f32x4*)&qks[nch * 520 + npg * 32 + s * 4];
            nv = fmaf(v[0], v[0], nv);
            nv = fmaf(v[1], v[1], nv);
            nv = fmaf(v[2], v[2], nv);
            nv = fmaf(v[3], v[3], nv);
        }
    }
    __syncthreads();
    float* gscr = qks;  // [16][624]
    const int wave = tid >> 6;
    if ((tid & 63) < 16) {
#pragma unroll
        for (int i = 0; i < 6; i++)
#pragma unroll
            for (int j = 0; j < 6; j++)
                gscr[wave * 624 + (tc * 6 + i) * 24 + (td * 6 + j)] = ga[i][j];
    }
    if (tid < 768) gscr[npg * 624 + 576 + nch] = nv;
    __syncthreads();
    if (tid < 624) {
        float s = 0.f;
#pragma unroll
        for (int w2 = 0; w2 < 16; w2++) s += gscr[w2 * 624 + tid];
        part[((size_t)(b * NHEADS + h) * 624 + tid) * 32 + stripe] = s;
    }
}

// ============ K3: reduce stripe partials (fixed order) ============
__global__ void k3_reduce(const float* __restrict__ part, float* __restrict__ G,
                          float* __restrict__ nq, float* __restrict__ nk) {
    int bh = blockIdx.x;
    int b = bh >> 3, h = bh & 7;
    int tid = threadIdx.x;
    int lane = tid & 63, wave = tid >> 6;
    int half = lane >> 5, sl = lane & 31;
    for (int tp = wave; tp < 312; tp += 4) {
        int ti = tp * 2 + half;
        float v = part[((size_t)bh * 624 + ti) * 32 + sl];
        v += __shfl_xor(v, 1, 64);
        v += __shfl_xor(v, 2, 64);
        v += __shfl_xor(v, 4, 64);
        v += __shfl_xor(v, 8, 64);
        v += __shfl_xor(v, 16, 64);
        if (sl == 0) {
            if (ti < 576) G[bh * 576 + ti] = v;
            else if (ti < 600) nq[b * DIMC + h * CDh + (ti - 576)] = v;
            else nk[b * DIMC + h * CDh + (ti - 600)] = v;
        }
    }
}

// ============ K4a: attn + 4 top-k sparse softmaxes -> A_eff ============
__global__ void k4a_attn(const float* __restrict__ G, const float* __restrict__ nq,
                         const float* __restrict__ nk, const float* __restrict__ temp,
                         const float* __restrict__ a1, const float* __restrict__ a2,
                         const float* __restrict__ a3, const float* __restrict__ a4,
                         float* __restrict__ Aeff) {
    int h = blockIdx.x, b = blockIdx.y;
    int bh = b * NHEADS + h;
    int r = threadIdx.x;
    if (r >= CDh) return;
    float t = temp[h];
    float aw[4] = {a1[0], a2[0], a3[0], a4[0]};
    const int kks[4] = {12, 16, 18, 19};
    float qn = fmaxf(sqrtf(nq[b * DIMC + h * CDh + r]), 1e-12f);
    float av[24];
    for (int d = 0; d < 24; d++) {
        float kn = fmaxf(sqrtf(nk[b * DIMC + h * CDh + d]), 1e-12f);
        av[d] = G[bh * 576 + r * 24 + d] / (qn * kn) * t;
    }
    int rank[24];
    float m = -1e30f;
    for (int d = 0; d < 24; d++) {
        int rk = 0;
        for (int e = 0; e < 24; e++)
            rk += (av[e] > av[d]) || (av[e] == av[d] && e < d);
        rank[d] = rk;
        m = fmaxf(m, av[d]);
    }
    float ex[24], outv[24];
    for (int d = 0; d < 24; d++) { ex[d] = expf(av[d] - m); outv[d] = 0.f; }
    for (int i = 0; i < 4; i++) {
        float Z = 0.f;
        for (int d = 0; d < 24; d++) if (rank[d] < kks[i]) Z += ex[d];
        float inv = aw[i] / Z;
        for (int d = 0; d < 24; d++) if (rank[d] < kks[i]) outv[d] += ex[d] * inv;
    }
    for (int d = 0; d < 24; d++) Aeff[(bh * 24 + r) * 24 + d] = outv[d];
}

// ============ K4b: M_b = W_proj @ blockdiag(A_eff) -> bf16 hi/lo ============
__global__ void k4b_mmat(const float* __restrict__ Wp, const float* __restrict__ Aeff,
                         ushort* __restrict__ Mh, ushort* __restrict__ Ml) {
    int b = blockIdx.x;
    int e0 = blockIdx.y * 6144;
    for (int e = e0 + threadIdx.x; e < e0 + 6144; e += 256) {
        int o = e / DIMC, j = e % DIMC;
        int h = j / CDh, d = j % CDh;
        const float* wrow = Wp + o * DIMC + h * CDh;
        const float* acol = Aeff + (size_t)((b * NHEADS + h) * CDh) * CDh + d;
        float s = 0.f;
        for (int c = 0; c < CDh; c++) s = fmaf(wrow[c], acol[c * CDh], s);
        size_t idx = ((size_t)b * DIMC + o) * DIMC + j;
        ushort hb = f2bf(s);
        Mh[idx] = hb;
        Ml[idx] = f2bf(s - bf2f(hb));
    }
}

// ============ K5m: y = M_b @ v + b_proj via split-bf16 MFMA ============
// grid (128 n-tiles of 128, 8 b), block 256 (4 waves; wave = 48 rows x 128 cols).
__global__ __launch_bounds__(256) void k5m(const float* __restrict__ v,
                                           const ushort* __restrict__ Mh,
                                           const ushort* __restrict__ Ml,
                                           const float* __restrict__ bias,
                                           float* __restrict__ y) {
    __shared__ float Bs[32 * 132];
    const int z = blockIdx.y;
    const float* vb = v + (size_t)z * DIMC * HWN;
    const ushort* Mhz = Mh + (size_t)z * DIMC * DIMC;
    const ushort* Mlz = Ml + (size_t)z * DIMC * DIMC;
    float* yb = y + (size_t)z * DIMC * HWN;
    const int n0 = blockIdx.x * 128;
    const int tid = threadIdx.x;
    const int wid = tid >> 6, lane = tid & 63;
    const int lr = lane & 15, lk = lane >> 4;
    const int mb = wid * 48;
    f32x4 acc[3][8];
#pragma unroll
    for (int i = 0; i < 3; i++)
#pragma unroll
        for (int j = 0; j < 8; j++) acc[i][j] = (f32x4)0.f;

    for (int kc = 0; kc < DIMC; kc += 32) {
        __syncthreads();
#pragma unroll
        for (int it = 0; it < 4; it++) {
            int f4 = tid + it * 256;
            int r = f4 >> 5, c4 = (f4 & 31) * 4;
            *(f32x4*)&Bs[r * 132 + c4] =
                *(const f32x4*)&vb[(size_t)(kc + r) * HWN + n0 + c4];
        }
        __syncthreads();
        short8 bh[8], bl[8];
#pragma unroll
        for (int j = 0; j < 8; j++) {
            int n = j * 16 + lr;
            S8U4 H, L;
#pragma unroll
            for (int p = 0; p < 4; p++) {
                float v0 = Bs[(lk * 8 + 2 * p) * 132 + n];
                float v1 = Bs[(lk * 8 + 2 * p + 1) * 132 + n];
                ushort h0 = f2bf(v0), h1 = f2bf(v1);
                ushort l0 = f2bf(v0 - bf2f(h0)), l1 = f2bf(v1 - bf2f(h1));
                H.u[p] = (uint)h0 | ((uint)h1 << 16);
                L.u[p] = (uint)l0 | ((uint)l1 << 16);
            }
            bh[j] = H.s; bl[j] = L.s;
        }
#pragma unroll
        for (int i = 0; i < 3; i++) {
            int row = mb + i * 16 + lr;
            const short8 ah = *(const short8*)&Mhz[(size_t)row * DIMC + kc + lk * 8];
            const short8 al = *(const short8*)&Mlz[(size_t)row * DIMC + kc + lk * 8];
#pragma unroll
            for (int j = 0; j < 8; j++) {
                acc[i][j] = __builtin_amdgcn_mfma_f32_16x16x32_bf16(ah, bh[j], acc[i][j], 0, 0, 0);
                acc[i][j] = __builtin_amdgcn_mfma_f32_16x16x32_bf16(ah, bl[j], acc[i][j], 0, 0, 0);
                acc[i][j] = __builtin_amdgcn_mfma_f32_16x16x32_bf16(al, bh[j], acc[i][j], 0, 0, 0);
            }
        }
    }
#pragma unroll
    for (int i = 0; i < 3; i++) {
        int rbase = mb + i * 16 + lk * 4;
#pragma unroll
        for (int r = 0; r < 4; r++) {
            int row = rbase + r;
            float bsv = bias[row];
#pragma unroll
            for (int j = 0; j < 8; j++) {
                int col = n0 + j * 16 + lr;
                yb[(size_t)row * HWN + col] = acc[i][j][r] + bsv;
            }
        }
    }
}

extern "C" void kernel_launch(void* const* d_in, const int* in_sizes, int n_in,
                              void* d_out, int out_size, void* d_ws, size_t ws_size,
                              hipStream_t stream) {
    const float* x     = (const float*)d_in[0];
    const float* wqkv  = (const float*)d_in[1];
    const float* bqkv  = (const float*)d_in[2];
    const float* wdw   = (const float*)d_in[3];
    const float* bdw   = (const float*)d_in[4];
    const float* wproj = (const float*)d_in[5];
    const float* bproj = (const float*)d_in[6];
    const float* temp  = (const float*)d_in[7];
    const float* a1    = (const float*)d_in[8];
    const float* a2    = (const float*)d_in[9];
    const float* a3    = (const float*)d_in[10];
    const float* a4    = (const float*)d_in[11];
    float* out = (float*)d_out;

    float* ws = (float*)d_ws;
    // float-unit offsets
    size_t o_part = 0;                                     // 64*624*32
    size_t o_G    = o_part + (size_t)64 * 624 * 32;        // 64*576
    size_t o_nq   = o_G + (size_t)64 * 576;
    size_t o_nk   = o_nq + (size_t)NBATCH * DIMC;
    size_t o_A    = o_nk + (size_t)NBATCH * DIMC;          // 64*576
    size_t o_Mh   = o_A + (size_t)64 * 576;                // 8*192*192 ushort = /2 floats
    size_t o_Ml   = o_Mh + (size_t)NBATCH * DIMC * DIMC / 2;
    size_t o_Wh   = o_Ml + (size_t)NBATCH * DIMC * DIMC / 2;   // 576*192 ushort
    size_t o_Wl   = o_Wh + (size_t)C3 * DIMC / 2;
    size_t o_vbuf = o_Wl + (size_t)C3 * DIMC / 2;          // 8*192*16384 (v conv'd)
    size_t o_vraw = o_vbuf + (size_t)NBATCH * DIMC * HWN;  // NZ*192*16384
    const size_t vraw_b = (size_t)DIMC * HWN;              // floats per batch
    const size_t qkb_b  = (size_t)384 * HWN;               // ushorts per batch (=/2 floats)

    size_t fl_loop  = o_vraw + vraw_b + qkb_b / 2;                       // ~134 MB
    size_t fl_batch = o_vraw + 8 * vraw_b + 8 * (qkb_b / 2);             // ~310 MB
    const bool batched = ws_size >= fl_batch * sizeof(float);

    float* part = ws + o_part;
    float* G    = ws + o_G;
    float* nq   = ws + o_nq;
    float* nk   = ws + o_nk;
    float* Aeff = ws + o_A;
    ushort* Mh  = (ushort*)(ws + o_Mh);
    ushort* Ml  = (ushort*)(ws + o_Ml);
    ushort* Wh  = (ushort*)(ws + o_Wh);
    ushort* Wl  = (ushort*)(ws + o_Wl);
    float* vbuf = ws + o_vbuf;
    float* vraw = ws + o_vraw;
    ushort* qkb = (ushort*)(ws + o_vraw + (batched ? 8 * vraw_b : vraw_b));

    (void)fl_loop;

    k0_prep<<<(C3 * DIMC + 255) / 256, 256, 0, stream>>>(wqkv, Wh, Wl, C3 * DIMC);

    if (batched) {
        k1m<<<dim3(256, 1, 8), 256, 0, stream>>>(x, Wh, Wl, bqkv, qkb, (long)qkb_b,
                                                 vraw, (long)vraw_b, 0);
        k2_dw<<<dim3(32, 8, 8), 1024, 0, stream>>>(qkb, (long)qkb_b, vraw, (long)vraw_b,
                                                   wdw, bdw, vbuf, part, 0);
    } else {
        for (int b = 0; b < NBATCH; b++) {
            k1m<<<dim3(256, 1, 1), 256, 0, stream>>>(x, Wh, Wl, bqkv, qkb, 0L,
                                                     vraw, 0L, b);
            k2_dw<<<dim3(32, 8, 1), 1024, 0, stream>>>(qkb, 0L, vraw, 0L,
                                                       wdw, bdw, vbuf, part, b);
        }
    }
    k3_reduce<<<64, 256, 0, stream>>>(part, G, nq, nk);
    k4a_attn<<<dim3(8, 8), 64, 0, stream>>>(G, nq, nk, temp, a1, a2, a3, a4, Aeff);
    k4b_mmat<<<dim3(8, 6), 256, 0, stream>>>(wproj, Aeff, Mh, Ml);
    k5m<<<dim3(128, 8), 256, 0, stream>>>(vbuf, Mh, Ml, bproj, out);
}